// Round 6
// baseline (21.990 us; speedup 1.0000x reference)
//
#include <hip/hip_runtime.h>
#include <math.h>

#define LN2_INV  1.4426950408889634f   // 1/ln(2)
#define INV_2PI  0.15915494309189535f  // 1/(2*pi)

typedef float v2f __attribute__((ext_vector_type(2)));

// out[h,l] = 2 * Re( sum_n coef[h,n] * S[h,n]^l ),  S = exp(dtA)
//
// Goertzel recurrence y(l+1) = 2Re(S)*y(l) - |S|^2*y(l-1), transcendental
// init only at each thread's l0. n processed in pairs (v2f, 2 independent
// chains). T=8 l's/thread -> 2048 blocks -> 8 waves/SIMD (TLP covers the
// LDS broadcast latency; no prefetch regs so VGPR <= 64 for 8 waves/SIMD).
#define T_PER_THREAD 8

__global__ __launch_bounds__(256, 8) void s4d_goertzel3(
    const float* __restrict__ log_dt,
    const float* __restrict__ C,
    const float* __restrict__ log_A_real,
    const float* __restrict__ A_imag,
    float* __restrict__ out,
    int Nh, int L, int blocksPerH)
{
    extern __shared__ float4 smem4[];
    float4* sA = smem4;          // {dtA_r/ln2, dtA_i/2pi, 2*coef_r, 2*coef_i}
    float4* sB = smem4 + Nh;     // {Re(S), Im(S), 2*Re(S), |S|^2}

    const int bid = blockIdx.x;
    const int h   = bid / blocksPerH;
    const int lb  = bid - h * blocksPerH;
    const int tid = threadIdx.x;

    // ---- per-(h,n) setup: first Nh lanes, accurate libm ----
    for (int n = tid; n < Nh; n += blockDim.x) {
        const float dt = expf(log_dt[h]);
        const float Ar = -expf(log_A_real[h * Nh + n]);
        const float Ai = A_imag[h * Nh + n];
        const float xr = Ar * dt;            // Re(dtA)
        const float xi = Ai * dt;            // Im(dtA)
        const float em = expf(xr);
        const float cs = cosf(xi);
        const float sn = sinf(xi);
        const float sr = em * cs;            // Re(S)
        const float si = em * sn;            // Im(S)
        const float er = sr - 1.0f;          // S-1
        const float ei = si;
        const float inv = 1.0f / fmaf(Ar, Ar, Ai * Ai);
        const float tr = fmaf(er, Ar,  ei * Ai) * inv;   // (S-1)/A
        const float ti = fmaf(ei, Ar, -er * Ai) * inv;
        const float c0 = C[(h * Nh + n) * 2 + 0];
        const float c1 = C[(h * Nh + n) * 2 + 1];
        const float cr = 2.0f * fmaf(c0, tr, -c1 * ti);  // 2*coef_r
        const float ci = 2.0f * fmaf(c0, ti,  c1 * tr);  // 2*coef_i
        sA[n] = make_float4(xr * LN2_INV, xi * INV_2PI, cr, ci);
        sB[n] = make_float4(sr, si, sr + sr, fmaf(sr, sr, si * si));
    }
    __syncthreads();

    const int l0 = lb * (256 * T_PER_THREAD) + tid * T_PER_THREAD;
    if (l0 >= L) return;
    const float lf0 = (float)l0;

    v2f acc2[T_PER_THREAD];
#pragma unroll
    for (int j = 0; j < T_PER_THREAD; ++j) acc2[j] = (v2f){0.0f, 0.0f};

    for (int n = 0; n < Nh; n += 2) {
        const float4 qa0 = sA[n],     qb0 = sB[n];
        const float4 qa1 = sA[n + 1], qb1 = sB[n + 1];

        // --- transcendental init for the two chains (only per (n,thread)) ---
        const float e0  = __builtin_amdgcn_exp2f(qa0.x * lf0);
        const float th0 = __builtin_amdgcn_fractf(qa0.y * lf0);
        const float s0  = __builtin_amdgcn_sinf(th0);
        const float c0  = __builtin_amdgcn_cosf(th0);
        const float e1  = __builtin_amdgcn_exp2f(qa1.x * lf0);
        const float th1 = __builtin_amdgcn_fractf(qa1.y * lf0);
        const float s1  = __builtin_amdgcn_sinf(th1);
        const float c1  = __builtin_amdgcn_cosf(th1);

        const float kr0 = e0 * c0, ki0 = e0 * s0;
        const float kr1 = e1 * c1, ki1 = e1 * s1;
        const float Pr0 = fmaf(qa0.z, kr0, -qa0.w * ki0);
        const float Pi0 = fmaf(qa0.z, ki0,  qa0.w * kr0);
        const float Pr1 = fmaf(qa1.z, kr1, -qa1.w * ki1);
        const float Pi1 = fmaf(qa1.z, ki1,  qa1.w * kr1);

        v2f y0 = (v2f){Pr0, Pr1};
        v2f y1 = (v2f){fmaf(Pr0, qb0.x, -Pi0 * qb0.y),
                       fmaf(Pr1, qb1.x, -Pi1 * qb1.y)};
        const v2f a2 = (v2f){qb0.z, qb1.z};   // 2*Re(S)
        const v2f nb = (v2f){qb0.w, qb1.w};   // |S|^2

        acc2[0] += y0;
        acc2[1] += y1;
#pragma unroll
        for (int j = 2; j < T_PER_THREAD; ++j) {
            const v2f t = nb * y0;                               // v_pk_mul_f32
            const v2f y = __builtin_elementwise_fma(a2, y1, -t); // v_pk_fma_f32
            acc2[j] += y;                                        // v_pk_add_f32
            y0 = y1;
            y1 = y;
        }
    }

    const size_t base = (size_t)h * (size_t)L + (size_t)l0;
    if (l0 + T_PER_THREAD <= L) {
#pragma unroll
        for (int k = 0; k < T_PER_THREAD / 4; ++k) {
            *reinterpret_cast<float4*>(&out[base + 4 * k]) = make_float4(
                acc2[4 * k + 0].x + acc2[4 * k + 0].y,
                acc2[4 * k + 1].x + acc2[4 * k + 1].y,
                acc2[4 * k + 2].x + acc2[4 * k + 2].y,
                acc2[4 * k + 3].x + acc2[4 * k + 3].y);
        }
    } else {
        for (int j = 0; j < T_PER_THREAD && l0 + j < L; ++j)
            out[base + j] = acc2[j].x + acc2[j].y;
    }
}

extern "C" void kernel_launch(void* const* d_in, const int* in_sizes, int n_in,
                              void* d_out, int out_size, void* d_ws, size_t ws_size,
                              hipStream_t stream)
{
    const float* log_dt     = (const float*)d_in[0];
    const float* C          = (const float*)d_in[1];
    const float* log_A_real = (const float*)d_in[2];
    const float* A_imag     = (const float*)d_in[3];
    float* out = (float*)d_out;

    const int H  = in_sizes[0];               // log_dt is (H,)
    const int Nh = in_sizes[2] / H;           // log_A_real is (H, Nh), Nh even
    const int L  = out_size / H;              // out is (H, L)

    const int lPerBlock  = 256 * T_PER_THREAD;            // 2048
    const int blocksPerH = (L + lPerBlock - 1) / lPerBlock;
    const int grid       = H * blocksPerH;
    const size_t smem    = 2 * (size_t)Nh * sizeof(float4);

    hipLaunchKernelGGL(s4d_goertzel3, dim3(grid), dim3(256), smem, stream,
                       log_dt, C, log_A_real, A_imag, out,
                       Nh, L, blocksPerH);
}

// Round 7
// 16.042 us; speedup vs baseline: 1.3708x; 1.3708x over previous
//
#include <hip/hip_runtime.h>
#include <math.h>

#define LN2_INV  1.4426950408889634f   // 1/ln(2)
#define INV_2PI  0.15915494309189535f  // 1/(2*pi)
#define NH 32
#define AB 64          // L = AB*AB = 4096; l = 64*a + b
#define PITCH 68       // LDS row pitch (floats): 68*4B=272B = 17*16B -> b128-aligned, bank-staggered

typedef float v4f __attribute__((ext_vector_type(4)));

// out[h, 64a+b] = sum_n Pr[n][a]*Qr[n][b] - Pi[n][a]*Qi[n][b]
//   S = exp(dtA), U = S^64
//   P[n][a] = 2*coef_n * U^a   (complex, planes Pr/Pi)
//   Q[n][b] = S^b              (complex, planes Qr/Qi)
// One block per head. Phase A: 32 lanes compute per-n constants (libm).
// Phase B: 256 threads build the 4 [32][64] planes (8 elements each).
// Phase C: thread t owns a 4x4 (a,b) tile -> 16 independent fp32 acc
// chains, 2 fma per n each; 4x ds_read_b128 per n (bank-conflict-free).
__global__ __launch_bounds__(256) void s4d_rank32(
    const float* __restrict__ log_dt,
    const float* __restrict__ C,
    const float* __restrict__ log_A_real,
    const float* __restrict__ A_imag,
    float* __restrict__ out,
    int L)
{
    __shared__ __align__(16) float sPr[NH][PITCH];
    __shared__ __align__(16) float sPi[NH][PITCH];
    __shared__ __align__(16) float sQr[NH][PITCH];
    __shared__ __align__(16) float sQi[NH][PITCH];
    __shared__ float sc[6][NH];   // ar1, ai1, ar64, ai64, cr, ci

    const int h = blockIdx.x;
    const int t = threadIdx.x;

    // ---- Phase A: per-n constants (accurate libm, 32 lanes) ----
    if (t < NH) {
        const int n = t;
        const float dt = expf(log_dt[h]);
        const float Ar = -expf(log_A_real[h * NH + n]);
        const float Ai = A_imag[h * NH + n];
        const float xr = Ar * dt;            // Re(dtA)
        const float xi = Ai * dt;            // Im(dtA)
        const float em = expf(xr);
        const float cs = cosf(xi);
        const float sn = sinf(xi);
        const float sr = em * cs;            // Re(S)
        const float si = em * sn;            // Im(S)
        const float er = sr - 1.0f;          // S-1
        const float ei = si;
        const float inv = 1.0f / fmaf(Ar, Ar, Ai * Ai);
        const float tr = fmaf(er, Ar,  ei * Ai) * inv;   // (S-1)/A
        const float ti = fmaf(ei, Ar, -er * Ai) * inv;
        const float c0 = C[(h * NH + n) * 2 + 0];
        const float c1 = C[(h * NH + n) * 2 + 1];
        sc[0][n] = xr * LN2_INV;             // per-step log2 magnitude
        sc[1][n] = xi * INV_2PI;             // per-step revolutions
        sc[2][n] = 64.0f * xr * LN2_INV;     // per-64-step
        sc[3][n] = 64.0f * xi * INV_2PI;
        sc[4][n] = 2.0f * fmaf(c0, tr, -c1 * ti);  // 2*coef_r
        sc[5][n] = 2.0f * fmaf(c0, ti,  c1 * tr);  // 2*coef_i
    }
    __syncthreads();

    // ---- Phase B: build planes; thread t -> n = t>>3, 8 consecutive elems ----
    {
        const int n  = t >> 3;
        const int e0 = (t & 7) * 8;
        const float ar1  = sc[0][n], ai1  = sc[1][n];
        const float ar64 = sc[2][n], ai64 = sc[3][n];
        const float cr   = sc[4][n], ci   = sc[5][n];
#pragma unroll
        for (int k = 0; k < 8; ++k) {
            const float x = (float)(e0 + k);
            // Q = S^b
            const float eq  = __builtin_amdgcn_exp2f(ar1 * x);
            const float thq = __builtin_amdgcn_fractf(ai1 * x);
            sQr[n][e0 + k] = eq * __builtin_amdgcn_cosf(thq);
            sQi[n][e0 + k] = eq * __builtin_amdgcn_sinf(thq);
            // P = 2*coef * U^a
            const float ep  = __builtin_amdgcn_exp2f(ar64 * x);
            const float thp = __builtin_amdgcn_fractf(ai64 * x);
            const float ur = ep * __builtin_amdgcn_cosf(thp);
            const float ui = ep * __builtin_amdgcn_sinf(thp);
            sPr[n][e0 + k] = fmaf(cr, ur, -ci * ui);
            sPi[n][e0 + k] = fmaf(cr, ui,  ci * ur);
        }
    }
    __syncthreads();

    // ---- Phase C: rank-32 outer product, 4x4 tile per thread ----
    const int a0 = (t >> 4) << 2;   // 0,4,...,60
    const int b0 = (t & 15) << 2;   // 0,4,...,60

    float acc[4][4];
#pragma unroll
    for (int i = 0; i < 4; ++i)
#pragma unroll
        for (int j = 0; j < 4; ++j) acc[i][j] = 0.0f;

#pragma unroll 4
    for (int n = 0; n < NH; ++n) {
        const v4f pr = *reinterpret_cast<const v4f*>(&sPr[n][a0]);
        const v4f pi = *reinterpret_cast<const v4f*>(&sPi[n][a0]);
        const v4f qr = *reinterpret_cast<const v4f*>(&sQr[n][b0]);
        const v4f qi = *reinterpret_cast<const v4f*>(&sQi[n][b0]);
#pragma unroll
        for (int i = 0; i < 4; ++i) {
#pragma unroll
            for (int j = 0; j < 4; ++j) {
                acc[i][j] = fmaf(pr[i], qr[j], acc[i][j]);
                acc[i][j] = fmaf(-pi[i], qi[j], acc[i][j]);
            }
        }
    }

    // ---- store: 4 float4 rows (lanes 0..15 cover 256B contiguous) ----
    float* op = out + (size_t)h * (size_t)L;
#pragma unroll
    for (int i = 0; i < 4; ++i) {
        const int l = (a0 + i) * AB + b0;
        if (l + 3 < L) {
            *reinterpret_cast<float4*>(&op[l]) =
                make_float4(acc[i][0], acc[i][1], acc[i][2], acc[i][3]);
        }
    }
}

extern "C" void kernel_launch(void* const* d_in, const int* in_sizes, int n_in,
                              void* d_out, int out_size, void* d_ws, size_t ws_size,
                              hipStream_t stream)
{
    const float* log_dt     = (const float*)d_in[0];
    const float* C          = (const float*)d_in[1];
    const float* log_A_real = (const float*)d_in[2];
    const float* A_imag     = (const float*)d_in[3];
    float* out = (float*)d_out;

    const int H = in_sizes[0];          // log_dt is (H,)
    const int L = out_size / H;         // out is (H, L); L = 4096 = 64*64

    hipLaunchKernelGGL(s4d_rank32, dim3(H), dim3(256), 0, stream,
                       log_dt, C, log_A_real, A_imag, out, L);
}

// Round 8
// 13.914 us; speedup vs baseline: 1.5805x; 1.1529x over previous
//
#include <hip/hip_runtime.h>
#include <math.h>

#define LN2_INV  1.4426950408889634f   // 1/ln(2)
#define INV_2PI  0.15915494309189535f  // 1/(2*pi)
#define NH 32
// L = 4096 = 64*64, l = 64*a + b.  Per head: out[a][b] = sum_k A[a][k]*B[k][b]
//   k=2n:   A[a][2n] = Pr[n][a], A[a][2n+1] = Pi[n][a]   (P = 2*coef*S^(64a))
//           B[2n][b] = Qr[n][b], B[2n+1][b] = -Qi[n][b]  (Q = S^b)
// => out = Re( sum_n 2*coef*S^(64a+b) )  (exact reformulation, fp32 staging)
//
// MFMA v_mfma_f32_32x32x16_bf16, 3-product bf16 split (Ah*Bh + Ah*Bl + Al*Bh)
// for ~fp32 accuracy. Operands built in registers (transcendental evals per
// lane); LDS holds only 32x8 consts per head (broadcast reads). 2 waves per
// head: wave owns row-block R (32 rows), computes C-tiles (R,0) and (R,1).

typedef float f32x16 __attribute__((ext_vector_type(16)));
typedef short bf16x8 __attribute__((ext_vector_type(8)));

__device__ __forceinline__ unsigned short bf16_rne(float x) {
    unsigned u = __float_as_uint(x);
    unsigned r = u + 0x7FFFu + ((u >> 16) & 1u);
    return (unsigned short)(r >> 16);
}
__device__ __forceinline__ float bf16f(unsigned short b) {
    return __uint_as_float(((unsigned)b) << 16);
}

__global__ __launch_bounds__(256, 2) void s4d_mfma(
    const float* __restrict__ log_dt,
    const float* __restrict__ C,
    const float* __restrict__ log_A_real,
    const float* __restrict__ A_imag,
    float* __restrict__ out)
{
    // per-n consts for the block's 2 heads:
    // [0] = {ar1 (log2-mag/step), ai1 (rev/step), 2*coef_r, 2*coef_i}
    // [1] = {Re(S^32), Im(S^32), 0, 0}
    __shared__ float4 sC[2][NH][2];

    const int t   = threadIdx.x;
    const int bid = blockIdx.x;

    // ---- Phase A: per-(head,n) constants (threads 0..63, accurate libm) ----
    if (t < 2 * NH) {
        const int hl = t >> 5;
        const int n  = t & 31;
        const int h  = 2 * bid + hl;
        const float dt = expf(log_dt[h]);
        const float Ar = -expf(log_A_real[h * NH + n]);
        const float Ai = A_imag[h * NH + n];
        const float xr = Ar * dt;            // Re(dtA)
        const float xi = Ai * dt;            // Im(dtA)
        const float em = expf(xr);
        const float cs = cosf(xi);
        const float sn = sinf(xi);
        const float sr = em * cs;            // Re(S)
        const float si = em * sn;            // Im(S)
        const float er = sr - 1.0f;          // S-1
        const float ei = si;
        const float inv = 1.0f / fmaf(Ar, Ar, Ai * Ai);
        const float tr = fmaf(er, Ar,  ei * Ai) * inv;   // (S-1)/A
        const float ti = fmaf(ei, Ar, -er * Ai) * inv;
        const float c0 = C[(h * NH + n) * 2 + 0];
        const float c1 = C[(h * NH + n) * 2 + 1];
        const float cr = 2.0f * fmaf(c0, tr, -c1 * ti);  // 2*coef_r
        const float ci = 2.0f * fmaf(c0, ti,  c1 * tr);  // 2*coef_i
        // S^32 (accurate libm; |32*xi| <= ~312 rad, libm range-reduces)
        const float e32 = expf(32.0f * xr);
        const float s32r = e32 * cosf(32.0f * xi);
        const float s32i = e32 * sinf(32.0f * xi);
        sC[hl][n][0] = make_float4(xr * LN2_INV, xi * INV_2PI, cr, ci);
        sC[hl][n][1] = make_float4(s32r, s32i, 0.0f, 0.0f);
    }
    __syncthreads();

    // ---- wave setup: wave w -> head hl=w>>1, row-block R=w&1 ----
    const int w    = t >> 6;
    const int hl   = w >> 1;
    const int R    = w & 1;
    const int h    = 2 * bid + hl;
    const int lane = t & 63;
    const int c    = lane & 31;     // A-row within block / B-col within block
    const int hi   = lane >> 5;     // lane half -> k-slot half
    const float fa = (float)(64 * (R * 32 + c));   // exponent arg for P rows
    const float fb = (float)c;                     // exponent arg for Q col-block 0

    f32x16 acc0, acc1;
#pragma unroll
    for (int i = 0; i < 16; ++i) { acc0[i] = 0.0f; acc1[i] = 0.0f; }

    // ---- 4 K-steps of 16 (k = 16s + 8*hi + slot; n = k>>1) ----
#pragma unroll
    for (int s = 0; s < 4; ++s) {
        const int nb = 8 * s + 4 * hi;
        float af[8], b0f[8], b1f[8];
#pragma unroll
        for (int j = 0; j < 4; ++j) {
            const int n = nb + j;
            const float4 q0 = sC[hl][n][0];   // ar1, ai1, cr, ci
            const float4 q1 = sC[hl][n][1];   // s32r, s32i
            // P = 2*coef * S^(64a)  (this lane's row)
            const float eP  = __builtin_amdgcn_exp2f(q0.x * fa);
            const float thP = __builtin_amdgcn_fractf(q0.y * fa);
            const float kr  = eP * __builtin_amdgcn_cosf(thP);
            const float ki  = eP * __builtin_amdgcn_sinf(thP);
            af[2 * j + 0] = fmaf(q0.z, kr, -q0.w * ki);   // Pr
            af[2 * j + 1] = fmaf(q0.z, ki,  q0.w * kr);   // Pi
            // Q = S^b for col-block 0; col-block 1 = Q * S^32
            const float eQ  = __builtin_amdgcn_exp2f(q0.x * fb);
            const float thQ = __builtin_amdgcn_fractf(q0.y * fb);
            const float qr  = eQ * __builtin_amdgcn_cosf(thQ);
            const float qi  = eQ * __builtin_amdgcn_sinf(thQ);
            b0f[2 * j + 0] = qr;
            b0f[2 * j + 1] = -qi;
            const float qr1 = fmaf(qr, q1.x, -qi * q1.y);
            const float qi1 = fmaf(qr, q1.y,  qi * q1.x);
            b1f[2 * j + 0] = qr1;
            b1f[2 * j + 1] = -qi1;
        }
        // bf16 hi/lo split (3-product emulation of fp32 matmul)
        bf16x8 Ah, Al, B0h, B0l, B1h, B1l;
#pragma unroll
        for (int i = 0; i < 8; ++i) {
            const unsigned short ah = bf16_rne(af[i]);
            Ah[i] = (short)ah;
            Al[i] = (short)bf16_rne(af[i] - bf16f(ah));
            const unsigned short b0 = bf16_rne(b0f[i]);
            B0h[i] = (short)b0;
            B0l[i] = (short)bf16_rne(b0f[i] - bf16f(b0));
            const unsigned short b1 = bf16_rne(b1f[i]);
            B1h[i] = (short)b1;
            B1l[i] = (short)bf16_rne(b1f[i] - bf16f(b1));
        }
        acc0 = __builtin_amdgcn_mfma_f32_32x32x16_bf16(Ah, B0h, acc0, 0, 0, 0);
        acc0 = __builtin_amdgcn_mfma_f32_32x32x16_bf16(Ah, B0l, acc0, 0, 0, 0);
        acc0 = __builtin_amdgcn_mfma_f32_32x32x16_bf16(Al, B0h, acc0, 0, 0, 0);
        acc1 = __builtin_amdgcn_mfma_f32_32x32x16_bf16(Ah, B1h, acc1, 0, 0, 0);
        acc1 = __builtin_amdgcn_mfma_f32_32x32x16_bf16(Ah, B1l, acc1, 0, 0, 0);
        acc1 = __builtin_amdgcn_mfma_f32_32x32x16_bf16(Al, B1h, acc1, 0, 0, 0);
    }

    // ---- store: C/D layout col=lane&31, row=(reg&3)+8*(reg>>2)+4*(lane>>5) ----
    float* op = out + (size_t)h * 4096;
#pragma unroll
    for (int r = 0; r < 16; ++r) {
        const int row = (r & 3) + 8 * (r >> 2) + 4 * hi;   // 0..31 in tile
        const int a   = R * 32 + row;
        op[a * 64 + c]      = acc0[r];
        op[a * 64 + 32 + c] = acc1[r];
    }
}

extern "C" void kernel_launch(void* const* d_in, const int* in_sizes, int n_in,
                              void* d_out, int out_size, void* d_ws, size_t ws_size,
                              hipStream_t stream)
{
    const float* log_dt     = (const float*)d_in[0];
    const float* C          = (const float*)d_in[1];
    const float* log_A_real = (const float*)d_in[2];
    const float* A_imag     = (const float*)d_in[3];
    float* out = (float*)d_out;

    const int H = in_sizes[0];          // 1024; L = out_size/H = 4096 = 64*64
    hipLaunchKernelGGL(s4d_mfma, dim3(H / 2), dim3(256), 0, stream,
                       log_dt, C, log_A_real, A_imag, out);
}